// Round 1
// baseline (3973.276 us; speedup 1.0000x reference)
//
#include <hip/hip_runtime.h>

#define C_ 48
#define H_ 64
#define W_ 128
#define K_ 5
#define PAD 4
#define RSW 136              // padded W row stride in LDS carry
#define RSH 72               // padded H row stride in LDS carry
#define NWGT (C_*C_*K_)      // 11520 floats
#define ROWW (C_*W_)         // 6144
#define ROWH (C_*H_)         // 3072
#define SLAB (C_*H_*W_)      // 393216 floats per batch

// ---- conv step along W: carry[C][W] in LDS, out = inp + conv(carry) + bias ----
__device__ __forceinline__ void stepW(
    float* __restrict__ sc, const float* __restrict__ sw,
    const float* __restrict__ inp, int inpCS,
    float b0, float b1, float b2,
    float* __restrict__ outrow, int wg, int og)
{
  const int w0 = wg * 8;
  const int o0 = og * 3;
  float xv[3][8];
#pragma unroll
  for (int j = 0; j < 3; ++j) {
    const float* ip = inp + (size_t)(o0 + j) * inpCS + w0;
    float4 a = *(const float4*)ip;
    float4 c = *(const float4*)(ip + 4);
    xv[j][0]=a.x; xv[j][1]=a.y; xv[j][2]=a.z; xv[j][3]=a.w;
    xv[j][4]=c.x; xv[j][5]=c.y; xv[j][6]=c.z; xv[j][7]=c.w;
  }
  float acc[3][8];
#pragma unroll
  for (int j = 0; j < 3; ++j)
#pragma unroll
    for (int w = 0; w < 8; ++w) acc[j][w] = 0.f;

#pragma unroll 2
  for (int i = 0; i < C_; ++i) {
    float cw[16];
    const float* cr = sc + i * RSW + w0;   // actual position w0-4 (PAD=4)
#pragma unroll
    for (int q = 0; q < 4; ++q) {
      float4 v = *(const float4*)(cr + 4 * q);
      cw[4*q+0]=v.x; cw[4*q+1]=v.y; cw[4*q+2]=v.z; cw[4*q+3]=v.w;
    }
#pragma unroll
    for (int j = 0; j < 3; ++j) {
      const float* wp = sw + ((o0 + j) * C_ + i) * K_;
#pragma unroll
      for (int k = 0; k < K_; ++k) {
        float wk = wp[k];
#pragma unroll
        for (int w = 0; w < 8; ++w)
          acc[j][w] += wk * cw[w + k + 2];
      }
    }
  }
  float bv0 = b0, bv1 = b1, bv2 = b2;
#pragma unroll
  for (int w = 0; w < 8; ++w) {
    acc[0][w] += bv0 + xv[0][w];
    acc[1][w] += bv1 + xv[1][w];
    acc[2][w] += bv2 + xv[2][w];
  }
  __syncthreads();
#pragma unroll
  for (int j = 0; j < 3; ++j)
#pragma unroll
    for (int w = 0; w < 8; ++w) {
      float v = acc[j][w];
      sc[(o0 + j) * RSW + PAD + w0 + w] = v;
      outrow[(size_t)(o0 + j) * W_ + w0 + w] = v;
    }
  __syncthreads();
}

// ---- conv step along H: carry[C][H] in LDS ----
__device__ __forceinline__ void stepH(
    float* __restrict__ sc, const float* __restrict__ sw,
    const float* __restrict__ inp, int inpCS,
    float b0, float b1, float b2,
    float* __restrict__ outrow, int wg, int og)
{
  const int h0 = wg * 4;
  const int o0 = og * 3;
  float xv[3][4];
#pragma unroll
  for (int j = 0; j < 3; ++j) {
    float4 a = *(const float4*)(inp + (size_t)(o0 + j) * inpCS + h0);
    xv[j][0]=a.x; xv[j][1]=a.y; xv[j][2]=a.z; xv[j][3]=a.w;
  }
  float acc[3][4];
#pragma unroll
  for (int j = 0; j < 3; ++j)
#pragma unroll
    for (int h = 0; h < 4; ++h) acc[j][h] = 0.f;

#pragma unroll 2
  for (int i = 0; i < C_; ++i) {
    float cw[12];
    const float* cr = sc + i * RSH + h0;   // actual position h0-4
#pragma unroll
    for (int q = 0; q < 3; ++q) {
      float4 v = *(const float4*)(cr + 4 * q);
      cw[4*q+0]=v.x; cw[4*q+1]=v.y; cw[4*q+2]=v.z; cw[4*q+3]=v.w;
    }
#pragma unroll
    for (int j = 0; j < 3; ++j) {
      const float* wp = sw + ((o0 + j) * C_ + i) * K_;
#pragma unroll
      for (int k = 0; k < K_; ++k) {
        float wk = wp[k];
#pragma unroll
        for (int h = 0; h < 4; ++h)
          acc[j][h] += wk * cw[h + k + 2];
      }
    }
  }
#pragma unroll
  for (int h = 0; h < 4; ++h) {
    acc[0][h] += b0 + xv[0][h];
    acc[1][h] += b1 + xv[1][h];
    acc[2][h] += b2 + xv[2][h];
  }
  __syncthreads();
#pragma unroll
  for (int j = 0; j < 3; ++j)
#pragma unroll
    for (int h = 0; h < 4; ++h) {
      float v = acc[j][h];
      sc[(o0 + j) * RSH + PAD + h0 + h] = v;
      outrow[(size_t)(o0 + j) * H_ + h0 + h] = v;
    }
  __syncthreads();
}

__device__ __forceinline__ void loadrowW(
    float* __restrict__ sc, const float* __restrict__ inp, int inpCS,
    float* __restrict__ outrow, int wg, int og)
{
  const int w0 = wg * 8;
  const int o0 = og * 3;
#pragma unroll
  for (int j = 0; j < 3; ++j) {
    const float* ip = inp + (size_t)(o0 + j) * inpCS + w0;
    float4 a = *(const float4*)ip;
    float4 c = *(const float4*)(ip + 4);
    float v[8] = {a.x,a.y,a.z,a.w,c.x,c.y,c.z,c.w};
#pragma unroll
    for (int w = 0; w < 8; ++w) {
      sc[(o0 + j) * RSW + PAD + w0 + w] = v[w];
      if (outrow) outrow[(size_t)(o0 + j) * W_ + w0 + w] = v[w];
    }
  }
  __syncthreads();
}

__device__ __forceinline__ void loadrowH(
    float* __restrict__ sc, const float* __restrict__ inp, int wg, int og)
{
  const int h0 = wg * 4;
  const int o0 = og * 3;
#pragma unroll
  for (int j = 0; j < 3; ++j) {
    float4 a = *(const float4*)(inp + (size_t)(o0 + j) * H_ + h0);
    sc[(o0 + j) * RSH + PAD + h0 + 0] = a.x;
    sc[(o0 + j) * RSH + PAD + h0 + 1] = a.y;
    sc[(o0 + j) * RSH + PAD + h0 + 2] = a.z;
    sc[(o0 + j) * RSH + PAD + h0 + 3] = a.w;
  }
  __syncthreads();
}

// generic tiled transpose: src[p*sP + c*sC + q]  ->  dst[q*dQ + c*dC + p]
__device__ void transpose_pcq(const float* __restrict__ src, float* __restrict__ dst,
                              int P, int Q, int sP, int sC, int dQ, int dC,
                              float* __restrict__ tile, int tid)
{
  const int tx = tid & 31, ty = tid >> 5;   // 32 x 8
  for (int c = 0; c < C_; ++c)
    for (int p0 = 0; p0 < P; p0 += 32)
      for (int q0 = 0; q0 < Q; q0 += 32) {
#pragma unroll
        for (int r = 0; r < 4; ++r)
          tile[(ty + 8*r) * 33 + tx] = src[(size_t)(p0 + ty + 8*r) * sP + c * sC + (q0 + tx)];
        __syncthreads();
#pragma unroll
        for (int r = 0; r < 4; ++r)
          dst[(size_t)(q0 + ty + 8*r) * dQ + c * dC + (p0 + tx)] = tile[tx * 33 + (ty + 8*r)];
        __syncthreads();
      }
}

__global__ __launch_bounds__(256) void scnn_all(
    const float* __restrict__ x,
    const float* __restrict__ dw, const float* __restrict__ db,
    const float* __restrict__ rw, const float* __restrict__ rb,
    const float* __restrict__ lw, const float* __restrict__ lb,
    float* __restrict__ out, float* __restrict__ ws)
{
  __shared__ float s_w[NWGT];        // 46080 B
  __shared__ float s_c[C_ * RSW];    // 26112 B (also transpose tile scratch)

  const int tid = threadIdx.x;
  const int b = blockIdx.x;
  const int wg = tid & 15;
  const int og = tid >> 4;
  const int o0 = og * 3;

  const float* xb = x + (size_t)b * SLAB;
  float* Dbuf = ws + (size_t)b * SLAB;           // D, then U (aliased), then Lt
  float* Tbuf = out + (size_t)b * SLAB;          // Ut, then R (aliased)

  // ================= DOWN =================
  for (int idx = tid; idx < NWGT; idx += 256) s_w[idx] = dw[idx];
  for (int idx = tid; idx < C_ * RSW; idx += 256) s_c[idx] = 0.f;
  __syncthreads();
  const float bd0 = db[o0], bd1 = db[o0+1], bd2 = db[o0+2];

  // d0 = x[:,:,0,:]
  loadrowW(s_c, xb, H_ * W_, Dbuf, wg, og);
  for (int h = 1; h < H_; ++h)
    stepW(s_c, s_w, xb + (size_t)h * W_, H_ * W_, bd0, bd1, bd2,
          Dbuf + (size_t)h * ROWW, wg, og);

  // ================= UP (down weights/bias; carry = D[63] already in LDS) ===
  // u[k] written to row 63-k; reads row 62-k (k<=62) or 63 (k=63): D rows still pristine.
  for (int k = 1; k < H_; ++k) {
    int ih = (k <= H_ - 2) ? (H_ - 2 - k) : (H_ - 1);
    stepW(s_c, s_w, Dbuf + (size_t)ih * ROWW, W_, bd0, bd1, bd2,
          Dbuf + (size_t)(H_ - 1 - k) * ROWW, wg, og);
  }

  // ======== TRANSPOSE A: U [h][c][w] -> Ut [w][c][h]  (Dbuf -> Tbuf) ========
  transpose_pcq(Dbuf, Tbuf, H_, W_, C_ * W_, W_, C_ * H_, H_, s_c, tid);

  // ================= RIGHT (conv along H; rows [C][H] in Tbuf, aliased R) ===
  for (int idx = tid; idx < NWGT; idx += 256) s_w[idx] = rw[idx];
  for (int idx = tid; idx < C_ * RSW; idx += 256) s_c[idx] = 0.f;
  __syncthreads();
  const float br0 = rb[o0], br1 = rb[o0+1], br2 = rb[o0+2];

  loadrowH(s_c, Tbuf, wg, og);   // r0 = Ut row 0 (already in place in Tbuf)
  for (int t = 1; t < W_; ++t)
    stepH(s_c, s_w, Tbuf + (size_t)t * ROWH, H_, br0, br1, br2,
          Tbuf + (size_t)t * ROWH, wg, og);   // write R[t] over Ut[t] (safe)

  // ================= LEFT (carry = R[127] already in LDS) ===================
  for (int idx = tid; idx < NWGT; idx += 256) s_w[idx] = lw[idx];
  __syncthreads();
  const float bl0 = lb[o0], bl1 = lb[o0+1], bl2 = lb[o0+2];

  // l0 = R[127]: copy row to Lt (Dbuf row 127)
  for (int idx = tid; idx < ROWH; idx += 256)
    Dbuf[(size_t)(W_ - 1) * ROWH + idx] = Tbuf[(size_t)(W_ - 1) * ROWH + idx];
  for (int k = 1; k < W_; ++k)
    stepH(s_c, s_w, Tbuf + (size_t)(W_ - 1 - k) * ROWH, H_, bl0, bl1, bl2,
          Dbuf + (size_t)(W_ - 1 - k) * ROWH, wg, og);   // Lt row 127-k = L[127-k]

  // ======== TRANSPOSE B: Lt [w][c][h] -> out [c][h][w]  (Dbuf -> out) =======
  transpose_pcq(Dbuf, out + (size_t)b * SLAB, W_, H_, C_ * H_, H_, W_, H_ * W_, s_c, tid);
}

extern "C" void kernel_launch(void* const* d_in, const int* in_sizes, int n_in,
                              void* d_out, int out_size, void* d_ws, size_t ws_size,
                              hipStream_t stream) {
  const float* x  = (const float*)d_in[0];
  const float* dw = (const float*)d_in[1];
  const float* db = (const float*)d_in[2];
  const float* rw = (const float*)d_in[3];
  const float* rb = (const float*)d_in[4];
  const float* lw = (const float*)d_in[5];
  const float* lb = (const float*)d_in[6];
  scnn_all<<<32, 256, 0, stream>>>(x, dw, db, rw, rb, lw, lb,
                                   (float*)d_out, (float*)d_ws);
}

// Round 2
// 516.311 us; speedup vs baseline: 7.6955x; 7.6955x over previous
//
#include <hip/hip_runtime.h>

#define B_ 32
#define C_ 48
#define H_ 64
#define W_ 128
#define K_ 5
#define SLAB (C_*H_*W_)         // 393216 floats per batch
#define CT_RS 72                // carry row stride (bf16 elems) -> 144B, 16B-aligned
#define CT_ROWS 132             // W_+4 halo rows (H-pass uses first 68)
#define NT 3                    // N tiles: 48/16
#define KB 10                   // K blocks: 5*64/32

typedef __attribute__((ext_vector_type(8))) short short8;
typedef __attribute__((ext_vector_type(4))) float f32x4;

__device__ __forceinline__ unsigned short f2bf(float f) {
  union { float f; unsigned u; } v; v.f = f;
  unsigned r = v.u + 0x7fffu + ((v.u >> 16) & 1u);   // RNE
  return (unsigned short)(r >> 16);
}

// Load weight fragments (B operand of MFMA) + per-lane bias into registers.
// B[k'][o] with k' = k*64 + i (i zero-padded 48->64), o = n*16 + (lane&15).
// Frag element j (lane l): k' = kb*32 + (l>>4)*8 + j.
__device__ __forceinline__ void load_wb(const float* __restrict__ wgt,
                                        const float* __restrict__ bias,
                                        short8 B[NT][KB], float bv[NT], int lane) {
  const int c = lane & 15, q = lane >> 4;
#pragma unroll
  for (int n = 0; n < NT; ++n) {
    bv[n] = bias[n * 16 + c];
#pragma unroll
    for (int kb = 0; kb < KB; ++kb) {
      short8 f;
#pragma unroll
      for (int j = 0; j < 8; ++j) {
        int kp = kb * 32 + q * 8 + j;
        int k = kp >> 6, i = kp & 63;
        float wv = (i < C_) ? wgt[(n * 16 + c) * (C_ * K_) + i * K_ + k] : 0.f;
        f[j] = (short)f2bf(wv);
      }
      B[n][kb] = f;
    }
  }
}

__device__ __forceinline__ void zero_carry(unsigned short* sct, int tid) {
  unsigned* p = (unsigned*)sct;
  for (int i = tid; i < CT_ROWS * CT_RS / 2; i += 256) p[i] = 0u;
  __syncthreads();
}

// Pass-initial step: carry = inp (no conv, no bias); optionally copy to outp.
template<int MTW>
__device__ __forceinline__ void init_step(unsigned short* sct,
                                          const float* inp, int inpRS,
                                          float* outp, int lane, int wid) {
  const int c = lane & 15, q = lane >> 4;
#pragma unroll
  for (int t = 0; t < MTW; ++t) {
    const int m0 = (wid * MTW + t) * 16;
#pragma unroll
    for (int n = 0; n < NT; ++n) {
#pragma unroll
      for (int r = 0; r < 4; ++r) {
        int row = m0 + 4 * q + r;
        float v = inp[(size_t)row * inpRS + n * 16 + c];
        outp[(size_t)row * C_ + n * 16 + c] = v;
        sct[(size_t)(row + 2) * CT_RS + n * 16 + c] = f2bf(v);
      }
    }
  }
  __syncthreads();
}

// One recurrence step:  out = inp + bias + conv(carry);  carry <- out.
// A (patch) from carry_t LDS via one ds_read_b128 per (Mt,Kb); B in regs.
// acc starts 0 so the global input loads hide under the MFMAs.
template<int MTW>
__device__ __forceinline__ void mfma_step(unsigned short* sct,
                                          const short8 B[NT][KB], const float bv[NT],
                                          const float* inp, int inpRS,
                                          float* outp, int lane, int wid) {
  const int c = lane & 15, q = lane >> 4;

  // issue input loads early; consumed only in the epilogue
  float xin[MTW][NT][4];
#pragma unroll
  for (int t = 0; t < MTW; ++t) {
    const int m0 = (wid * MTW + t) * 16;
#pragma unroll
    for (int n = 0; n < NT; ++n) {
      const float* p = inp + (size_t)(m0 + 4 * q) * inpRS + n * 16 + c;
#pragma unroll
      for (int r = 0; r < 4; ++r) xin[t][n][r] = p[(size_t)r * inpRS];
    }
  }

  f32x4 acc[MTW][NT];
#pragma unroll
  for (int t = 0; t < MTW; ++t)
#pragma unroll
    for (int n = 0; n < NT; ++n) acc[t][n] = (f32x4){0.f, 0.f, 0.f, 0.f};

#pragma unroll
  for (int kb = 0; kb < KB; ++kb) {
#pragma unroll
    for (int t = 0; t < MTW; ++t) {
      const int m0 = (wid * MTW + t) * 16;
      // A row = m0 + (lane&15); mem row = row + k (halo +2 folded with k-2)
      const unsigned short* ap =
          sct + (size_t)(m0 + c + (kb >> 1)) * CT_RS + (kb & 1) * 32 + q * 8;
      short8 a = *(const short8*)ap;
#pragma unroll
      for (int n = 0; n < NT; ++n)
        acc[t][n] = __builtin_amdgcn_mfma_f32_16x16x32_bf16(a, B[n][kb], acc[t][n], 0, 0, 0);
    }
  }
  __syncthreads();   // all carry reads done

#pragma unroll
  for (int t = 0; t < MTW; ++t) {
    const int m0 = (wid * MTW + t) * 16;
#pragma unroll
    for (int n = 0; n < NT; ++n) {
#pragma unroll
      for (int r = 0; r < 4; ++r) {
        int row = m0 + 4 * q + r;
        float v = acc[t][n][r] + xin[t][n][r] + bv[n];
        outp[(size_t)row * C_ + n * 16 + c] = v;
        sct[(size_t)(row + 2) * CT_RS + n * 16 + c] = f2bf(v);
      }
    }
  }
  __syncthreads();   // carry visible for next step
}

__global__ __launch_bounds__(256, 1) void scnn_mfma(
    float* ws,                       // xT [b][h][w][c], then R/L [b][t][h][c] (aliased)
    const float* __restrict__ dw, const float* __restrict__ db,
    const float* __restrict__ rw, const float* __restrict__ rb,
    const float* __restrict__ lw, const float* __restrict__ lb,
    float* __restrict__ DU)          // d_out: D then U slabs [b][h][w][c]
{
  __shared__ unsigned short sct[CT_ROWS * CT_RS];
  const int tid = threadIdx.x, lane = tid & 63, wid = tid >> 6;
  const int b = blockIdx.x;
  float* xb = ws + (size_t)b * SLAB;   // consumed by DOWN before R overwrites
  float* rl = ws + (size_t)b * SLAB;
  float* du = DU + (size_t)b * SLAB;

  short8 B[NT][KB];
  float bv[NT];

  // ---------------- DOWN: d[h] = x[h] + convW(d[h-1]) ----------------
  load_wb(dw, db, B, bv, lane);
  zero_carry(sct, tid);
  init_step<2>(sct, xb, C_, du, lane, wid);                       // d0 = x[0]
  for (int h = 1; h < H_; ++h)
    mfma_step<2>(sct, B, bv, xb + (size_t)h * (W_ * C_), C_,
                 du + (size_t)h * (W_ * C_), lane, wid);

  // ---------------- UP: same weights; carry already = D[63] ----------
  for (int k = 1; k < H_; ++k) {
    int ih = (k <= H_ - 2) ? (H_ - 2 - k) : (H_ - 1);
    mfma_step<2>(sct, B, bv, du + (size_t)ih * (W_ * C_), C_,
                 du + (size_t)(H_ - 1 - k) * (W_ * C_), lane, wid);
  }

  // ---------------- RIGHT: r[t] = U[...,t] + convH(r[t-1]) -----------
  load_wb(rw, rb, B, bv, lane);
  zero_carry(sct, tid);
  init_step<1>(sct, du, W_ * C_, rl, lane, wid);                  // r0 = U slice t=0
  for (int t = 1; t < W_; ++t)
    mfma_step<1>(sct, B, bv, du + (size_t)t * C_, W_ * C_,
                 rl + (size_t)t * (H_ * C_), lane, wid);

  // ---------------- LEFT: carry = R[127]; L[127]=R[127] in place -----
  load_wb(lw, lb, B, bv, lane);
  for (int k = 1; k < W_; ++k)
    mfma_step<1>(sct, B, bv, rl + (size_t)(W_ - 1 - k) * (H_ * C_), C_,
                 rl + (size_t)(W_ - 1 - k) * (H_ * C_), lane, wid);
}

// x [b][c][h][w] -> xT [b][h][w][c]
__global__ __launch_bounds__(256) void xpose_chw_hwc(const float* __restrict__ x,
                                                     float* __restrict__ xT) {
  __shared__ float t[C_ * 129];
  const int bh = blockIdx.x, b = bh >> 6, h = bh & 63;
  const float* src = x + (size_t)b * SLAB + (size_t)h * W_;
  float* dst = xT + (size_t)b * SLAB + (size_t)h * (W_ * C_);
  for (int i = threadIdx.x; i < C_ * W_; i += 256) {
    int c = i >> 7, w = i & 127;
    t[c * 129 + w] = src[(size_t)c * (H_ * W_) + w];
  }
  __syncthreads();
  for (int i = threadIdx.x; i < C_ * W_; i += 256) {
    int w = i / C_, c = i - w * C_;
    dst[i] = t[c * 129 + w];
  }
}

// L [b][w][h][c] -> out [b][c][h][w]
__global__ __launch_bounds__(256) void xpose_whc_chw(const float* __restrict__ L,
                                                     float* __restrict__ out) {
  __shared__ float t[W_ * 49];
  const int bh = blockIdx.x, b = bh >> 6, h = bh & 63;
  const float* src = L + (size_t)b * SLAB + (size_t)h * C_;
  float* dst = out + (size_t)b * SLAB + (size_t)h * W_;
  for (int i = threadIdx.x; i < W_ * C_; i += 256) {
    int w = i / C_, c = i - w * C_;
    t[w * 49 + c] = src[(size_t)w * (H_ * C_) + c];
  }
  __syncthreads();
  for (int i = threadIdx.x; i < C_ * W_; i += 256) {
    int c = i >> 7, w = i & 127;
    dst[(size_t)c * (H_ * W_) + w] = t[w * 49 + c];
  }
}

extern "C" void kernel_launch(void* const* d_in, const int* in_sizes, int n_in,
                              void* d_out, int out_size, void* d_ws, size_t ws_size,
                              hipStream_t stream) {
  const float* x  = (const float*)d_in[0];
  const float* dw = (const float*)d_in[1];
  const float* db = (const float*)d_in[2];
  const float* rw = (const float*)d_in[3];
  const float* rb = (const float*)d_in[4];
  const float* lw = (const float*)d_in[5];
  const float* lb = (const float*)d_in[6];
  float* DU = (float*)d_out;
  float* WS = (float*)d_ws;

  xpose_chw_hwc<<<B_ * H_, 256, 0, stream>>>(x, WS);
  scnn_mfma<<<B_, 256, 0, stream>>>(WS, dw, db, rw, rb, lw, lb, DU);
  xpose_whc_chw<<<B_ * H_, 256, 0, stream>>>(WS, DU);
}

// Round 3
// 445.431 us; speedup vs baseline: 8.9201x; 1.1591x over previous
//
#include <hip/hip_runtime.h>
#include <hip/hip_bf16.h>

#define B_ 32
#define C_ 48
#define H_ 64
#define W_ 128
#define K_ 5
#define SLAB (C_*H_*W_)
#define RS 72                 // carry row stride (bf16) = 144B
#define ROWS 132              // W_+4 halo rows
#define KB 10                 // K blocks: 5*64/32
#define WC (W_*C_)
#define HC (H_*C_)

typedef __attribute__((ext_vector_type(8))) short short8;
typedef __attribute__((ext_vector_type(4))) float f32x4;

__device__ __forceinline__ void lbar() {
  asm volatile("s_waitcnt lgkmcnt(0)\n\ts_barrier" ::: "memory");
}

__device__ __forceinline__ unsigned short f2bf(float f) {
  union { float f; unsigned u; } v; v.f = f;
  unsigned r = v.u + 0x7fffu + ((v.u >> 16) & 1u);
  return (unsigned short)(r >> 16);
}

__device__ __forceinline__ unsigned pk2(float a, float b) {
  union { __hip_bfloat162 h; unsigned u; } z;
  z.h = __float22bfloat162_rn(float2{a, b});
  return z.u;                         // low16 = bf(a), high16 = bf(b)
}

// Weights as MFMA *A* operand: A[m][k'], m = mt*16 + (lane&15),
// k' = kb*32 + q*8 + j  ->  tap k = k'>>6, in-chan i = k'&63 (zero-pad 48..63).
__device__ __forceinline__ void load_wA(const float* __restrict__ wgt,
                                        const float* __restrict__ bias,
                                        short8 A[3][KB], float bv[3][4],
                                        int l15, int q) {
#pragma unroll
  for (int mt = 0; mt < 3; ++mt) {
#pragma unroll
    for (int r = 0; r < 4; ++r) bv[mt][r] = bias[mt * 16 + 4 * q + r];
#pragma unroll
    for (int kb = 0; kb < KB; ++kb) {
      short8 f;
#pragma unroll
      for (int j = 0; j < 8; ++j) {
        int kp = kb * 32 + q * 8 + j, k = kp >> 6, i = kp & 63;
        f[j] = (i < C_) ? (short)f2bf(wgt[(mt * 16 + l15) * (C_ * K_) + i * K_ + k])
                        : (short)0;
      }
      A[mt][kb] = f;
    }
  }
}

// xin: per (nt,mt) one float4 = inp[row][c0..c0+3], row = n0+nt*16+(lane&15)
template<int NTW>
__device__ __forceinline__ void load_xin(float4 xv[NTW][3], const float* __restrict__ inp,
                                         int lRS, int n0, int l15, int c0) {
#pragma unroll
  for (int nt = 0; nt < NTW; ++nt) {
    const float* p = inp + (size_t)(n0 + nt * 16 + l15) * lRS;
#pragma unroll
    for (int mt = 0; mt < 3; ++mt)
      xv[nt][mt] = *(const float4*)(p + mt * 16 + c0);
  }
}

// One step: acc = W * carry(scr); out = acc + xin + bias; write out (global,
// float4) + new carry (scw, b64 bf16). One light barrier.
template<int NTW>
__device__ __forceinline__ void do_step(const unsigned short* __restrict__ scr,
                                        unsigned short* __restrict__ scw,
                                        const short8 A[3][KB], const float bv[3][4],
                                        const float4 xv[NTW][3],
                                        float* __restrict__ outp,
                                        int n0, int l15, int q, int c0) {
  f32x4 acc[NTW][3];
#pragma unroll
  for (int nt = 0; nt < NTW; ++nt)
#pragma unroll
    for (int mt = 0; mt < 3; ++mt) acc[nt][mt] = (f32x4){0.f, 0.f, 0.f, 0.f};

#pragma unroll
  for (int kb = 0; kb < KB; ++kb) {
    short8 pf[NTW];
#pragma unroll
    for (int nt = 0; nt < NTW; ++nt)
      pf[nt] = *(const short8*)(scr + (size_t)(n0 + nt * 16 + l15 + (kb >> 1)) * RS
                                + (kb & 1) * 32 + q * 8);
#pragma unroll
    for (int nt = 0; nt < NTW; ++nt)
#pragma unroll
      for (int mt = 0; mt < 3; ++mt)
        acc[nt][mt] = __builtin_amdgcn_mfma_f32_16x16x32_bf16(A[mt][kb], pf[nt],
                                                              acc[nt][mt], 0, 0, 0);
  }

#pragma unroll
  for (int nt = 0; nt < NTW; ++nt) {
    const int row = n0 + nt * 16 + l15;
#pragma unroll
    for (int mt = 0; mt < 3; ++mt) {
      float4 v;
      v.x = acc[nt][mt][0] + xv[nt][mt].x + bv[mt][0];
      v.y = acc[nt][mt][1] + xv[nt][mt].y + bv[mt][1];
      v.z = acc[nt][mt][2] + xv[nt][mt].z + bv[mt][2];
      v.w = acc[nt][mt][3] + xv[nt][mt].w + bv[mt][3];
      *(float4*)(outp + (size_t)row * C_ + mt * 16 + c0) = v;
      uint2 pk; pk.x = pk2(v.x, v.y); pk.y = pk2(v.z, v.w);
      *(uint2*)(scw + (size_t)(row + 2) * RS + mt * 16 + c0) = pk;
    }
  }
  lbar();
}

// Pass-initial: carry = inp, out = inp (no conv, no bias).
template<int NTW>
__device__ __forceinline__ void init_store(unsigned short* __restrict__ scw,
                                           const float* __restrict__ inp, int lRS,
                                           float* __restrict__ outp,
                                           int n0, int l15, int q, int c0) {
  float4 xv[NTW][3];
  load_xin<NTW>(xv, inp, lRS, n0, l15, c0);
#pragma unroll
  for (int nt = 0; nt < NTW; ++nt) {
    const int row = n0 + nt * 16 + l15;
#pragma unroll
    for (int mt = 0; mt < 3; ++mt) {
      float4 v = xv[nt][mt];
      *(float4*)(outp + (size_t)row * C_ + mt * 16 + c0) = v;
      uint2 pk; pk.x = pk2(v.x, v.y); pk.y = pk2(v.z, v.w);
      *(uint2*)(scw + (size_t)(row + 2) * RS + mt * 16 + c0) = pk;
    }
  }
  lbar();
}

// Software-pipelined pass: prefetch xin one step ahead; double-buffered carry.
template<int NTW, class FIN, class FOUT>
__device__ __forceinline__ void run_pass(unsigned short* sb, int& p,
                                         const short8 A[3][KB], const float bv[3][4],
                                         int nsteps, FIN inadr, int lRS, FOUT outadr,
                                         int n0, int l15, int q, int c0) {
  float4 xa[NTW][3], xb[NTW][3];
  load_xin<NTW>(xa, inadr(1), lRS, n0, l15, c0);
  for (int s = 1; s <= nsteps; s += 2) {
    {
      int sn = (s + 1 <= nsteps) ? s + 1 : nsteps;
      load_xin<NTW>(xb, inadr(sn), lRS, n0, l15, c0);
      __builtin_amdgcn_sched_barrier(0x38F);   // pin VMEM: prefetch can't sink
      do_step<NTW>(sb + (size_t)p * (ROWS * RS), sb + (size_t)(p ^ 1) * (ROWS * RS),
                   A, bv, xa, outadr(s), n0, l15, q, c0);
      p ^= 1;
    }
    if (s + 1 <= nsteps) {
      int sn = (s + 2 <= nsteps) ? s + 2 : nsteps;
      load_xin<NTW>(xa, inadr(sn), lRS, n0, l15, c0);
      __builtin_amdgcn_sched_barrier(0x38F);
      do_step<NTW>(sb + (size_t)p * (ROWS * RS), sb + (size_t)(p ^ 1) * (ROWS * RS),
                   A, bv, xb, outadr(s + 1), n0, l15, q, c0);
      p ^= 1;
    }
  }
}

__global__ __launch_bounds__(256, 1) void scnn_mfma(
    float* ws,                       // xT [b][h][w][c]; then R/L [b][t][h][c] (alias)
    const float* __restrict__ dw, const float* __restrict__ db,
    const float* __restrict__ rw, const float* __restrict__ rb,
    const float* __restrict__ lw, const float* __restrict__ lb,
    float* __restrict__ DU)          // d_out: D/U slabs [b][h][w][c]
{
  __shared__ unsigned short sb[2 * ROWS * RS];
  const int tid = threadIdx.x, lane = tid & 63, wid = tid >> 6;
  const int l15 = lane & 15, q = lane >> 4, c0 = 4 * q;
  const int b = blockIdx.x;
  float* xbuf = ws + (size_t)b * SLAB;
  float* rl   = ws + (size_t)b * SLAB;
  float* du   = DU + (size_t)b * SLAB;
  const int n0w = wid * 32, n0h = wid * 16;

  short8 A[3][KB];
  float bv[3][4];
  int p = 0;

  // ---------------- DOWN ----------------
  load_wA(dw, db, A, bv, l15, q);
  { unsigned* z = (unsigned*)sb; for (int i = tid; i < ROWS * RS; i += 256) z[i] = 0u; }
  __syncthreads();
  init_store<2>(sb, xbuf, C_, du, n0w, l15, q, c0);               // p=0 holds d0
  run_pass<2>(sb, p, A, bv, H_ - 1,
              [&](int s) { return xbuf + (size_t)s * WC; }, C_,
              [&](int s) { return du + (size_t)s * WC; }, n0w, l15, q, c0);
  __syncthreads();

  // ---------------- UP (down weights; carry = D[63] persists) ----------------
  run_pass<2>(sb, p, A, bv, H_ - 1,
              [&](int s) { int ih = (s <= H_ - 2) ? (H_ - 2 - s) : (H_ - 1);
                           return du + (size_t)ih * WC; }, C_,
              [&](int s) { return du + (size_t)(H_ - 1 - s) * WC; }, n0w, l15, q, c0);
  __syncthreads();

  // ---------------- RIGHT ----------------
  load_wA(rw, rb, A, bv, l15, q);
  { unsigned* z = (unsigned*)sb; for (int i = tid; i < ROWS * RS; i += 256) z[i] = 0u; }
  __syncthreads();
  p = 0;
  init_store<1>(sb, du, WC, rl, n0h, l15, q, c0);                 // r0 = U[...,0]
  run_pass<1>(sb, p, A, bv, W_ - 1,
              [&](int s) { return du + (size_t)s * C_; }, WC,
              [&](int s) { return rl + (size_t)s * HC; }, n0h, l15, q, c0);
  __syncthreads();

  // ---------------- LEFT (carry = R[127]; L[127]=R[127] already in place) ----
  load_wA(lw, lb, A, bv, l15, q);
  run_pass<1>(sb, p, A, bv, W_ - 1,
              [&](int s) { return rl + (size_t)(W_ - 1 - s) * HC; }, C_,
              [&](int s) { return rl + (size_t)(W_ - 1 - s) * HC; }, n0h, l15, q, c0);
}

// x [b][c][h][w] -> xT [b][h][w][c]
__global__ __launch_bounds__(256) void xpose_chw_hwc(const float* __restrict__ x,
                                                     float* __restrict__ xT) {
  __shared__ float t[C_ * 129];
  const int bh = blockIdx.x, b = bh >> 6, h = bh & 63;
  const float* src = x + (size_t)b * SLAB + (size_t)h * W_;
  float* dst = xT + (size_t)b * SLAB + (size_t)h * (W_ * C_);
  for (int i = threadIdx.x; i < C_ * W_; i += 256) {
    int c = i >> 7, w = i & 127;
    t[c * 129 + w] = src[(size_t)c * (H_ * W_) + w];
  }
  __syncthreads();
  for (int i = threadIdx.x; i < C_ * W_; i += 256) {
    int w = i / C_, c = i - w * C_;
    dst[i] = t[c * 129 + w];
  }
}

// L [b][w][h][c] -> out [b][c][h][w]
__global__ __launch_bounds__(256) void xpose_whc_chw(const float* __restrict__ L,
                                                     float* __restrict__ out) {
  __shared__ float t[W_ * 49];
  const int bh = blockIdx.x, b = bh >> 6, h = bh & 63;
  const float* src = L + (size_t)b * SLAB + (size_t)h * C_;
  float* dst = out + (size_t)b * SLAB + (size_t)h * W_;
  for (int i = threadIdx.x; i < W_ * C_; i += 256) {
    int w = i / C_, c = i - w * C_;
    t[w * 49 + c] = src[(size_t)w * (H_ * C_) + c];
  }
  __syncthreads();
  for (int i = threadIdx.x; i < C_ * W_; i += 256) {
    int c = i >> 7, w = i & 127;
    dst[(size_t)c * (H_ * W_) + w] = t[w * 49 + c];
  }
}

extern "C" void kernel_launch(void* const* d_in, const int* in_sizes, int n_in,
                              void* d_out, int out_size, void* d_ws, size_t ws_size,
                              hipStream_t stream) {
  const float* x  = (const float*)d_in[0];
  const float* dw = (const float*)d_in[1];
  const float* db = (const float*)d_in[2];
  const float* rw = (const float*)d_in[3];
  const float* rb = (const float*)d_in[4];
  const float* lw = (const float*)d_in[5];
  const float* lb = (const float*)d_in[6];
  float* DU = (float*)d_out;
  float* WS = (float*)d_ws;

  xpose_chw_hwc<<<B_ * H_, 256, 0, stream>>>(x, WS);
  scnn_mfma<<<B_, 256, 0, stream>>>(WS, dw, db, rw, rb, lw, lb, DU);
  xpose_whc_chw<<<B_ * H_, 256, 0, stream>>>(WS, DU);
}